// Round 6
// baseline (239.848 us; speedup 1.0000x reference)
//
#include <hip/hip_runtime.h>

#define Bn 4096
#define Dn 66
#define Hn 512

typedef __attribute__((ext_vector_type(8))) short short8;
typedef __attribute__((ext_vector_type(4))) float f32x4;

__device__ __forceinline__ unsigned short f2bf(float x) {
    union { float f; unsigned u; } v; v.f = x;
    unsigned r = v.u + 0x7fffu + ((v.u >> 16) & 1u);   // RNE
    return (unsigned short)(r >> 16);
}
__device__ __forceinline__ float bf2f(unsigned short h) {
    union { float f; unsigned u; } v; v.u = ((unsigned)h) << 16; return v.f;
}

// Layouts (unchanged from verified kernels):
//   A-frag tile ks: lane l holds A[l&15][ks*32 + (l>>4)*8 + j]  at (ks*64 + l)*8 + j
//   WQ interleaved B-frag tile (ct, ks): W2-frag at ((ct*16+ks)*64+l)*16 + 0..7,
//       Cm-frag at +8..15
//   W3P B-frag tile (jt, ks): ((jt*16+ks)*64 + l)*8 + j
//
// NEW this round: WQ/W3P are replicated 8x (one copy per XCD-slot bid&7).
// Block bid packs tile (bid>>3)*16+wv of copy bid&7 and reads ONLY copy bid&7.
// Per-copy counters: exactly 32 blocks have each bid&7 value -> 512 wave-signals
// per counter, INDEPENDENT of hardware block->XCD mapping (correctness holds
// under any mapping; bid%8==XCD only affects L2 locality).

__global__ __launch_bounds__(1024, 4) void k_single(
    const float* __restrict__ xs, const float* __restrict__ tt,
    const float* __restrict__ W1, const float* __restrict__ b1,
    const float* __restrict__ W2, const float* __restrict__ b2,
    const float* __restrict__ W3, const float* __restrict__ b3,
    unsigned short* __restrict__ WQ, unsigned short* __restrict__ W3P,
    unsigned int* __restrict__ doneCtr,
    float* __restrict__ out)
{
    __shared__ float sX[67*16];                          // x~^T staging [i][r]
    __shared__ __align__(16) unsigned short sA[8192];    // h1 hi A-frags (16 KB)
    __shared__ __align__(16) unsigned short sS[8192];    // s1 A-frags   (16 KB)
    __shared__ __align__(16) unsigned short sH[8192];    // h2 hi (16 KB)
    __shared__ __align__(16) unsigned short sL[8192];    // h2 lo (16 KB)
    __shared__ float sRed[16*16];

    const int tid = threadIdx.x, lane = tid & 63, wv = tid >> 6;   // wv 0..15
    const int bid = blockIdx.x;
    const int xcd = bid & 7, lb = bid >> 3;              // copy slot, local index
    const int rt = bid, r0 = rt*16;
    const int n = lane & 15, kg = lane >> 4;
    const int rot = (rt >> 3) & 15;

    unsigned short* WQx  = WQ  + (size_t)xcd * 524288;   // 1 MB per copy
    unsigned short* W3Px = W3P + (size_t)xcd * 65536;    // 128 KB per copy
    unsigned int*   ctr  = doneCtr + xcd * 16;           // 64 B apart

    // ---- stage x~^T (row 66 = t) into sX[i*16 + r] ----
    for (int idx = tid; idx < 67*16; idx += 1024) {
        const int i = idx >> 4, r = idx & 15;
        sX[idx] = (i < Dn) ? xs[(size_t)(r0+r)*Dn + i] : tt[r0+r];
    }
    __syncthreads();

    // ---- pack: EVERY wave packs WQ tile lb*16+wv of this copy ----
    {
        const int tix = lb*16 + wv;                // 0..511 = (ct 0..31, ks 0..15)
        const int ct = tix >> 4, ks = tix & 15;
        const int c = ct*16 + n;
        const int abase = ks*32 + kg*8;
        float w2v[8], m[8];
        #pragma unroll
        for (int j = 0; j < 8; ++j) {
            w2v[j] = W2[(size_t)(abase + j)*Hn + c];
            m[j] = 0.f;
        }
        const float* w3row = &W3[(size_t)c * Dn];
        #pragma unroll 4
        for (int i = 0; i < Dn; ++i) {
            const float w3 = w3row[i];
            const float4 w1a = *(const float4*)&W1[(size_t)i*Hn + abase];
            const float4 w1b = *(const float4*)&W1[(size_t)i*Hn + abase + 4];
            m[0] = fmaf(w3, w1a.x, m[0]); m[1] = fmaf(w3, w1a.y, m[1]);
            m[2] = fmaf(w3, w1a.z, m[2]); m[3] = fmaf(w3, w1a.w, m[3]);
            m[4] = fmaf(w3, w1b.x, m[4]); m[5] = fmaf(w3, w1b.y, m[5]);
            m[6] = fmaf(w3, w1b.z, m[6]); m[7] = fmaf(w3, w1b.w, m[7]);
        }
        short8 pw, pc;
        #pragma unroll
        for (int j = 0; j < 8; ++j) {
            pw[j] = (short)f2bf(w2v[j]);
            pc[j] = (short)f2bf(w2v[j] * m[j]);
        }
        const size_t off = ((size_t)tix*64 + lane)*16;
        *(short8*)&WQx[off]     = pw;
        *(short8*)&WQx[off + 8] = pc;
    }
    // ---- W3P pack: blocks lb<5, all 16 waves (80 tiles per copy) ----
    if (lb < 5) {
        const int tix = lb*16 + wv;                // 0..79 = (jt 0..4, ks 0..15)
        const int ks = tix & 15;
        const int j_out = (tix >> 4)*16 + n;
        const int abase = ks*32 + kg*8;
        short8 p;
        #pragma unroll
        for (int j = 0; j < 8; ++j)
            p[j] = (j_out < Dn) ? (short)f2bf(W3[(size_t)(abase + j)*Dn + j_out]) : (short)0;
        *(short8*)&W3Px[((size_t)tix*64 + lane)*8] = p;
    }
    __threadfence();                                // release: wave's pack stores
    if (lane == 0)
        __hip_atomic_fetch_add(ctr, 1u, __ATOMIC_RELAXED, __HIP_MEMORY_SCOPE_AGENT);

    // ---- phase A: z1 = [x,t]@W1 + b1 (fp32 VALU); wave wv owns ks-tile wv ----
    {
        const int rg = lane & 7, cg = lane >> 3;
        const int ks = wv;
        const int c0 = ks*32 + cg*4;
        const int irot = (rt >> 3) & 31;
        float z[2][4];
        {
            const float4 b4 = *(const float4*)&b1[c0];
            z[0][0]=b4.x; z[0][1]=b4.y; z[0][2]=b4.z; z[0][3]=b4.w;
            z[1][0]=b4.x; z[1][1]=b4.y; z[1][2]=b4.z; z[1][3]=b4.w;
        }
        #pragma unroll 4
        for (int s = 0; s < 67; ++s) {
            int i = s + irot; if (i >= 67) i -= 67;
            const float2 xf = *(const float2*)&sX[i*16 + 2*rg];
            const float4 wA = *(const float4*)&W1[(size_t)i*Hn + c0];
            const float ww[4] = {wA.x, wA.y, wA.z, wA.w};
            #pragma unroll
            for (int j = 0; j < 4; ++j) {
                z[0][j] = fmaf(xf.x, ww[j], z[0][j]);
                z[1][j] = fmaf(xf.y, ww[j], z[1][j]);
            }
        }
        const int kgrp = cg >> 1, joff = (cg & 1)*4;
        #pragma unroll
        for (int rr = 0; rr < 2; ++rr) {
            const int r = 2*rg + rr;
            ushort4 phi, ps;
            unsigned short* PH = (unsigned short*)&phi;
            unsigned short* PS = (unsigned short*)&ps;
            #pragma unroll
            for (int j = 0; j < 4; ++j) {
                const float zv = z[rr][j];
                const float sg = 1.f / (1.f + __expf(-zv));
                PH[j] = f2bf(zv * sg);
                PS[j] = f2bf(sg * (1.f + zv * (1.f - sg)));
            }
            const int off = (ks*64 + r + 16*kgrp)*8 + joff;
            *(ushort4*)&sA[off] = phi;
            *(ushort4*)&sS[off] = ps;
        }
    }

    // ---- wait: all 512 pack waves of THIS copy signaled. Relaxed poll. ----
    if (tid == 0) {
        while (__hip_atomic_load(ctr, __ATOMIC_RELAXED, __HIP_MEMORY_SCOPE_AGENT) < 512u)
            __builtin_amdgcn_s_sleep(8);
        __threadfence();                            // acquire once
    }
    __syncthreads();                                // also covers LDS A-frags

    // ---- phase B: z2 = h1hi@W2 + b2, v = s1'@Cmat; A/S from LDS, WQx prefetched ----
    const int ctb = wv*2;
    f32x4 zac[2], vac[2];
    #pragma unroll
    for (int ti = 0; ti < 2; ++ti) {
        const float bz = b2[(ctb + ti)*16 + n];
        zac[ti] = (f32x4){bz, bz, bz, bz};
        vac[ti] = (f32x4){0.f, 0.f, 0.f, 0.f};
    }
    short8 wbuf[2][2], qbuf[2][2], abuf[2], sbuf[2];
    {
        const int ks0 = rot;
        abuf[0] = *(const short8*)&sA[(ks0*64 + lane)*8];
        sbuf[0] = *(const short8*)&sS[(ks0*64 + lane)*8];
        #pragma unroll
        for (int ti = 0; ti < 2; ++ti) {
            const size_t wo = ((size_t)((ctb + ti)*16 + ks0)*64 + lane)*16;
            wbuf[0][ti] = *(const short8*)&WQx[wo];
            qbuf[0][ti] = *(const short8*)&WQx[wo + 8];
        }
    }
    #pragma unroll
    for (int s = 0; s < 16; ++s) {
        const int cur = s & 1, nxt = cur ^ 1;
        if (s < 15) {
            const int ksn = (s + 1 + rot) & 15;
            abuf[nxt] = *(const short8*)&sA[(ksn*64 + lane)*8];
            sbuf[nxt] = *(const short8*)&sS[(ksn*64 + lane)*8];
            #pragma unroll
            for (int ti = 0; ti < 2; ++ti) {
                const size_t wo = ((size_t)((ctb + ti)*16 + ksn)*64 + lane)*16;
                wbuf[nxt][ti] = *(const short8*)&WQx[wo];
                qbuf[nxt][ti] = *(const short8*)&WQx[wo + 8];
            }
        }
        #pragma unroll
        for (int ti = 0; ti < 2; ++ti) {
            zac[ti] = __builtin_amdgcn_mfma_f32_16x16x32_bf16(abuf[cur], wbuf[cur][ti], zac[ti], 0, 0, 0);
            vac[ti] = __builtin_amdgcn_mfma_f32_16x16x32_bf16(sbuf[cur], qbuf[cur][ti], vac[ti], 0, 0, 0);
        }
    }

    // ---- epilogue: h2 hi/lo -> LDS; dp partial reduce ----
    float dp[4] = {0.f, 0.f, 0.f, 0.f};
    #pragma unroll
    for (int ti = 0; ti < 2; ++ti) {
        const int c = (ctb + ti)*16 + n;
        const int ks2 = c >> 5, kg2 = (c >> 3) & 3, j2 = c & 7;
        #pragma unroll
        for (int q = 0; q < 4; ++q) {
            const float z2 = zac[ti][q];
            const float sg = 1.f / (1.f + __expf(-z2));
            const float h2 = z2 * sg;
            dp[q] = fmaf(sg * (1.f + z2 * (1.f - sg)), vac[ti][q], dp[q]);
            const unsigned short hh = f2bf(h2);
            const int o = (ks2*64 + (kg*4 + q) + 16*kg2)*8 + j2;
            sH[o] = hh;
            sL[o] = f2bf(h2 - bf2f(hh));
        }
    }
    #pragma unroll
    for (int q = 0; q < 4; ++q) {
        float v = dp[q];
        v += __shfl_xor(v, 1, 64);
        v += __shfl_xor(v, 2, 64);
        v += __shfl_xor(v, 4, 64);
        v += __shfl_xor(v, 8, 64);
        if (n == 0) sRed[wv*16 + kg*4 + q] = v;
    }
    __syncthreads();

    // ---- divergence finalize ----
    if (tid < 16) {
        float s = 0.f;
        #pragma unroll
        for (int q = 0; q < 16; ++q) s += sRed[q*16 + tid];
        out[(size_t)Bn*Dn + r0 + tid] = -s;
    }

    // ---- phase C: out = h2 @ W3 + b3 (waves 0..4); rotated ks ----
    if (wv < 5) {
        const int jt = wv;
        const int j = jt*16 + n;
        const float bj = (j < Dn) ? b3[j] : 0.f;
        f32x4 oac = (f32x4){bj, bj, bj, bj};
        #pragma unroll 4
        for (int s = 0; s < 16; ++s) {
            const int ks = (s + rot) & 15;
            const int aoff = (ks*64 + lane)*8;
            const short8 ahi = *(const short8*)&sH[aoff];
            const short8 alo = *(const short8*)&sL[aoff];
            const short8 wf  = *(const short8*)&W3Px[((size_t)(jt*16 + ks)*64 + lane)*8];
            oac = __builtin_amdgcn_mfma_f32_16x16x32_bf16(ahi, wf, oac, 0, 0, 0);
            oac = __builtin_amdgcn_mfma_f32_16x16x32_bf16(alo, wf, oac, 0, 0, 0);
        }
        if (j < Dn) {
            #pragma unroll
            for (int q = 0; q < 4; ++q)
                out[(size_t)(r0 + kg*4 + q)*Dn + j] = oac[q];
        }
    }
}

extern "C" void kernel_launch(void* const* d_in, const int* in_sizes, int n_in,
                              void* d_out, int out_size, void* d_ws, size_t ws_size,
                              hipStream_t stream)
{
    const float* xs = (const float*)d_in[0];
    const float* t  = (const float*)d_in[1];
    const float* W1 = (const float*)d_in[2];
    const float* b1 = (const float*)d_in[3];
    const float* W2 = (const float*)d_in[4];
    const float* b2 = (const float*)d_in[5];
    const float* W3 = (const float*)d_in[6];
    const float* b3 = (const float*)d_in[7];
    float* out = (float*)d_out;

    char* ws = (char*)d_ws;
    unsigned short* WQ   = (unsigned short*)(ws);                 // 8 x 1 MB copies
    unsigned short* W3P  = (unsigned short*)(ws + 8388608);       // 8 x 128 KB copies
    unsigned int*  doneCtr = (unsigned int*)(ws + 9437184);       // 8 x 64 B counters

    hipMemsetAsync(doneCtr, 0, 512, stream);
    k_single<<<256, 1024, 0, stream>>>(xs, t, W1, b1, W2, b2, W3, b3,
                                       WQ, W3P, doneCtr, out);
}

// Round 7
// 104.125 us; speedup vs baseline: 2.3035x; 2.3035x over previous
//
#include <hip/hip_runtime.h>

#define Bn 4096
#define Dn 66
#define Hn 512

typedef __attribute__((ext_vector_type(8))) short short8;
typedef __attribute__((ext_vector_type(4))) float f32x4;

__device__ __forceinline__ unsigned short f2bf(float x) {
    union { float f; unsigned u; } v; v.f = x;
    unsigned r = v.u + 0x7fffu + ((v.u >> 16) & 1u);   // RNE
    return (unsigned short)(r >> 16);
}
__device__ __forceinline__ float bf2f(unsigned short h) {
    union { float f; unsigned u; } v; v.u = ((unsigned)h) << 16; return v.f;
}

// Layouts (unchanged from verified kernels):
//   A-frag tile ks: lane l holds A[l&15][ks*32 + (l>>4)*8 + j]  at (ks*64 + l)*8 + j
//   WQ interleaved B-frag tile (ct, ks): W2-frag at ((ct*16+ks)*64+l)*16 + 0..7,
//       Cm-frag at +8..15
//   W3P B-frag tile (jt, ks): ((jt*16+ks)*64 + l)*8 + j

// ============ k_pack (138 blocks x 512): weight packs, 2x parallel ============
// wave-task = bid*8+wv:
//   0..1023  : WQ half-tile: tix = t>>1 (ct,ks), jh = t&1 -> j's jh*4..jh*4+3
//   1024..1103: W3P tile tix = t-1024
__global__ __launch_bounds__(512, 2) void k_pack(
    const float* __restrict__ W1, const float* __restrict__ W2,
    const float* __restrict__ W3,
    unsigned short* __restrict__ WQ, unsigned short* __restrict__ W3P)
{
    const int tid = threadIdx.x;
    const int lane = tid & 63, wv = tid >> 6;          // wv 0..7
    const int task = blockIdx.x * 8 + wv;              // 0..1103
    const int n = lane & 15, kg = lane >> 4;

    if (task < 1024) {
        const int tix = task >> 1;                     // 0..511 = (ct, ks)
        const int jh  = task & 1;
        const int ct = tix >> 4, ks = tix & 15;
        const int c = ct*16 + n;
        const int abase = ks*32 + kg*8 + jh*4;
        float w2v[4], m[4];
        #pragma unroll
        for (int j = 0; j < 4; ++j) {
            w2v[j] = W2[(size_t)(abase + j)*Hn + c];
            m[j] = 0.f;
        }
        const float* w3row = &W3[(size_t)c * Dn];
        #pragma unroll 4
        for (int i = 0; i < Dn; ++i) {
            const float w3 = w3row[i];
            const float4 w1a = *(const float4*)&W1[(size_t)i*Hn + abase];
            m[0] = fmaf(w3, w1a.x, m[0]); m[1] = fmaf(w3, w1a.y, m[1]);
            m[2] = fmaf(w3, w1a.z, m[2]); m[3] = fmaf(w3, w1a.w, m[3]);
        }
        ushort4 pw, pc;
        unsigned short* PW = (unsigned short*)&pw;
        unsigned short* PC = (unsigned short*)&pc;
        #pragma unroll
        for (int j = 0; j < 4; ++j) {
            PW[j] = f2bf(w2v[j]);
            PC[j] = f2bf(w2v[j] * m[j]);
        }
        const size_t off = ((size_t)tix*64 + lane)*16 + jh*4;
        *(ushort4*)&WQ[off]     = pw;
        *(ushort4*)&WQ[off + 8] = pc;
    } else if (task < 1104) {
        const int tix = task - 1024;                   // 0..79 = (jt 0..4, ks 0..15)
        const int ks = tix & 15;
        const int j_out = (tix >> 4)*16 + n;
        const int abase = ks*32 + kg*8;
        short8 p;
        #pragma unroll
        for (int j = 0; j < 8; ++j)
            p[j] = (j_out < Dn) ? (short)f2bf(W3[(size_t)(abase + j)*Dn + j_out]) : (short)0;
        *(short8*)&W3P[((size_t)tix*64 + lane)*8] = p;
    }
}

// ============ k_fused: phases A+B+C, grid 256 x 1024 (verified structure) ============
__global__ __launch_bounds__(1024, 4) void k_fused(
    const float* __restrict__ xs, const float* __restrict__ tt,
    const float* __restrict__ W1, const float* __restrict__ b1,
    const unsigned short* __restrict__ WQ, const float* __restrict__ b2,
    const unsigned short* __restrict__ W3P, const float* __restrict__ b3,
    float* __restrict__ out)
{
    __shared__ float sX[67*16];                          // x~^T staging [i][r]
    __shared__ __align__(16) unsigned short sA[8192];    // h1 hi A-frags (16 KB)
    __shared__ __align__(16) unsigned short sS[8192];    // s1 A-frags   (16 KB)
    __shared__ __align__(16) unsigned short sH[8192];    // h2 hi (16 KB)
    __shared__ __align__(16) unsigned short sL[8192];    // h2 lo (16 KB)
    __shared__ float sRed[16*16];

    const int tid = threadIdx.x, lane = tid & 63, wv = tid >> 6;   // wv 0..15
    const int rt = blockIdx.x, r0 = rt*16;
    const int n = lane & 15, kg = lane >> 4;
    const int rot = (rt >> 3) & 15;

    // ---- stage x~^T (row 66 = t) into sX[i*16 + r] ----
    for (int idx = tid; idx < 67*16; idx += 1024) {
        const int i = idx >> 4, r = idx & 15;
        sX[idx] = (i < Dn) ? xs[(size_t)(r0+r)*Dn + i] : tt[r0+r];
    }
    __syncthreads();

    // ---- phase A: z1 = [x,t]@W1 + b1 (fp32 VALU); wave wv owns ks-tile wv ----
    {
        const int rg = lane & 7, cg = lane >> 3;
        const int ks = wv;
        const int c0 = ks*32 + cg*4;
        const int irot = (rt >> 3) & 31;
        float z[2][4];
        {
            const float4 b4 = *(const float4*)&b1[c0];
            z[0][0]=b4.x; z[0][1]=b4.y; z[0][2]=b4.z; z[0][3]=b4.w;
            z[1][0]=b4.x; z[1][1]=b4.y; z[1][2]=b4.z; z[1][3]=b4.w;
        }
        #pragma unroll 4
        for (int s = 0; s < 67; ++s) {
            int i = s + irot; if (i >= 67) i -= 67;
            const float2 xf = *(const float2*)&sX[i*16 + 2*rg];
            const float4 wA = *(const float4*)&W1[(size_t)i*Hn + c0];
            const float ww[4] = {wA.x, wA.y, wA.z, wA.w};
            #pragma unroll
            for (int j = 0; j < 4; ++j) {
                z[0][j] = fmaf(xf.x, ww[j], z[0][j]);
                z[1][j] = fmaf(xf.y, ww[j], z[1][j]);
            }
        }
        const int kgrp = cg >> 1, joff = (cg & 1)*4;
        #pragma unroll
        for (int rr = 0; rr < 2; ++rr) {
            const int r = 2*rg + rr;
            ushort4 phi, ps;
            unsigned short* PH = (unsigned short*)&phi;
            unsigned short* PS = (unsigned short*)&ps;
            #pragma unroll
            for (int j = 0; j < 4; ++j) {
                const float zv = z[rr][j];
                const float sg = 1.f / (1.f + __expf(-zv));
                PH[j] = f2bf(zv * sg);
                PS[j] = f2bf(sg * (1.f + zv * (1.f - sg)));
            }
            const int off = (ks*64 + r + 16*kgrp)*8 + joff;
            *(ushort4*)&sA[off] = phi;
            *(ushort4*)&sS[off] = ps;
        }
    }
    __syncthreads();

    // ---- phase B: z2 = h1hi@W2 + b2, v = s1'@Cmat; depth-2 ring prefetch ----
    const int ctb = wv*2;
    f32x4 zac[2], vac[2];
    #pragma unroll
    for (int ti = 0; ti < 2; ++ti) {
        const float bz = b2[(ctb + ti)*16 + n];
        zac[ti] = (f32x4){bz, bz, bz, bz};
        vac[ti] = (f32x4){0.f, 0.f, 0.f, 0.f};
    }
    short8 wA[3][2], wQ[3][2], aR[3], sR[3];
    #pragma unroll
    for (int p = 0; p < 2; ++p) {
        const int ksp = (p + rot) & 15;
        aR[p] = *(const short8*)&sA[(ksp*64 + lane)*8];
        sR[p] = *(const short8*)&sS[(ksp*64 + lane)*8];
        #pragma unroll
        for (int ti = 0; ti < 2; ++ti) {
            const size_t wo = ((size_t)((ctb + ti)*16 + ksp)*64 + lane)*16;
            wA[p][ti] = *(const short8*)&WQ[wo];
            wQ[p][ti] = *(const short8*)&WQ[wo + 8];
        }
    }
    #pragma unroll
    for (int s = 0; s < 16; ++s) {
        const int cur = s % 3;
        if (s < 14) {
            const int nx = (s + 2) % 3;
            const int ksn = (s + 2 + rot) & 15;
            aR[nx] = *(const short8*)&sA[(ksn*64 + lane)*8];
            sR[nx] = *(const short8*)&sS[(ksn*64 + lane)*8];
            #pragma unroll
            for (int ti = 0; ti < 2; ++ti) {
                const size_t wo = ((size_t)((ctb + ti)*16 + ksn)*64 + lane)*16;
                wA[nx][ti] = *(const short8*)&WQ[wo];
                wQ[nx][ti] = *(const short8*)&WQ[wo + 8];
            }
        }
        #pragma unroll
        for (int ti = 0; ti < 2; ++ti) {
            zac[ti] = __builtin_amdgcn_mfma_f32_16x16x32_bf16(aR[cur], wA[cur][ti], zac[ti], 0, 0, 0);
            vac[ti] = __builtin_amdgcn_mfma_f32_16x16x32_bf16(sR[cur], wQ[cur][ti], vac[ti], 0, 0, 0);
        }
    }

    // ---- epilogue: h2 hi/lo -> LDS; dp partial reduce ----
    float dp[4] = {0.f, 0.f, 0.f, 0.f};
    #pragma unroll
    for (int ti = 0; ti < 2; ++ti) {
        const int c = (ctb + ti)*16 + n;
        const int ks2 = c >> 5, kg2 = (c >> 3) & 3, j2 = c & 7;
        #pragma unroll
        for (int q = 0; q < 4; ++q) {
            const float z2 = zac[ti][q];
            const float sg = 1.f / (1.f + __expf(-z2));
            const float h2 = z2 * sg;
            dp[q] = fmaf(sg * (1.f + z2 * (1.f - sg)), vac[ti][q], dp[q]);
            const unsigned short hh = f2bf(h2);
            const int o = (ks2*64 + (kg*4 + q) + 16*kg2)*8 + j2;
            sH[o] = hh;
            sL[o] = f2bf(h2 - bf2f(hh));
        }
    }
    #pragma unroll
    for (int q = 0; q < 4; ++q) {
        float v = dp[q];
        v += __shfl_xor(v, 1, 64);
        v += __shfl_xor(v, 2, 64);
        v += __shfl_xor(v, 4, 64);
        v += __shfl_xor(v, 8, 64);
        if (n == 0) sRed[wv*16 + kg*4 + q] = v;
    }
    __syncthreads();

    // ---- divergence finalize ----
    if (tid < 16) {
        float s = 0.f;
        #pragma unroll
        for (int q = 0; q < 16; ++q) s += sRed[q*16 + tid];
        out[(size_t)Bn*Dn + r0 + tid] = -s;
    }

    // ---- phase C: out = h2 @ W3 + b3 (waves 0..4); depth-1 W3P prefetch ----
    if (wv < 5) {
        const int jt = wv;
        const int j = jt*16 + n;
        const float bj = (j < Dn) ? b3[j] : 0.f;
        f32x4 oac = (f32x4){bj, bj, bj, bj};
        short8 wf[2];
        wf[0] = *(const short8*)&W3P[((size_t)(jt*16 + rot)*64 + lane)*8];
        #pragma unroll
        for (int s = 0; s < 16; ++s) {
            const int cur = s & 1;
            if (s < 15) {
                const int ksn = (s + 1 + rot) & 15;
                wf[cur ^ 1] = *(const short8*)&W3P[((size_t)(jt*16 + ksn)*64 + lane)*8];
            }
            const int ks = (s + rot) & 15;
            const int aoff = (ks*64 + lane)*8;
            const short8 ahi = *(const short8*)&sH[aoff];
            const short8 alo = *(const short8*)&sL[aoff];
            oac = __builtin_amdgcn_mfma_f32_16x16x32_bf16(ahi, wf[cur], oac, 0, 0, 0);
            oac = __builtin_amdgcn_mfma_f32_16x16x32_bf16(alo, wf[cur], oac, 0, 0, 0);
        }
        if (j < Dn) {
            #pragma unroll
            for (int q = 0; q < 4; ++q)
                out[(size_t)(r0 + kg*4 + q)*Dn + j] = oac[q];
        }
    }
}

extern "C" void kernel_launch(void* const* d_in, const int* in_sizes, int n_in,
                              void* d_out, int out_size, void* d_ws, size_t ws_size,
                              hipStream_t stream)
{
    const float* xs = (const float*)d_in[0];
    const float* t  = (const float*)d_in[1];
    const float* W1 = (const float*)d_in[2];
    const float* b1 = (const float*)d_in[3];
    const float* W2 = (const float*)d_in[4];
    const float* b2 = (const float*)d_in[5];
    const float* W3 = (const float*)d_in[6];
    const float* b3 = (const float*)d_in[7];
    float* out = (float*)d_out;

    char* ws = (char*)d_ws;
    unsigned short* WQ  = (unsigned short*)(ws);             // 1 MB interleaved W2|Cm
    unsigned short* W3P = (unsigned short*)(ws + 1048576);   // 80 KB

    k_pack <<<138, 512,  0, stream>>>(W1, W2, W3, WQ, W3P);
    k_fused<<<256, 1024, 0, stream>>>(xs, t, W1, b1, WQ, b2, W3P, b3, out);
}

// Round 8
// 103.237 us; speedup vs baseline: 2.3233x; 1.0086x over previous
//
#include <hip/hip_runtime.h>

#define Bn 4096
#define Dn 66
#define Hn 512

typedef __attribute__((ext_vector_type(8))) short short8;
typedef __attribute__((ext_vector_type(4))) float f32x4;

__device__ __forceinline__ unsigned short f2bf(float x) {
    union { float f; unsigned u; } v; v.f = x;
    unsigned r = v.u + 0x7fffu + ((v.u >> 16) & 1u);   // RNE
    return (unsigned short)(r >> 16);
}
__device__ __forceinline__ float bf2f(unsigned short h) {
    union { float f; unsigned u; } v; v.u = ((unsigned)h) << 16; return v.f;
}

// Layouts (unchanged from verified kernels):
//   A-frag tile ks: lane l holds A[l&15][ks*32 + (l>>4)*8 + j]  at (ks*64 + l)*8 + j
//   WQ interleaved B-frag tile (ct, ks): W2-frag at ((ct*16+ks)*64+l)*16 + 0..7,
//       Cm-frag at +8..15
//   W3P B-frag tile (jt, ks): ((jt*16+ks)*64 + l)*8 + j

// ============ k_pack (1104 blocks x 64): one wave-task per block ============
// task = blockIdx.x:
//   0..1023  : WQ half-tile: tix = t>>1 (ct,ks), jh = t&1 -> j's jh*4..jh*4+3
//   1024..1103: W3P tile tix = t-1024
// 1104 single-wave blocks spread over all 256 CUs (vs 138 8-wave blocks on
// 138 CUs in round 7): same wave count, 2x the CU VMEM ports on the cold
// weight stream.
__global__ __launch_bounds__(64, 8) void k_pack(
    const float* __restrict__ W1, const float* __restrict__ W2,
    const float* __restrict__ W3,
    unsigned short* __restrict__ WQ, unsigned short* __restrict__ W3P)
{
    const int lane = threadIdx.x & 63;
    const int task = blockIdx.x;                       // 0..1103
    const int n = lane & 15, kg = lane >> 4;

    if (task < 1024) {
        const int tix = task >> 1;                     // 0..511 = (ct, ks)
        const int jh  = task & 1;
        const int ct = tix >> 4, ks = tix & 15;
        const int c = ct*16 + n;
        const int abase = ks*32 + kg*8 + jh*4;
        float w2v[4], m[4];
        #pragma unroll
        for (int j = 0; j < 4; ++j) {
            w2v[j] = W2[(size_t)(abase + j)*Hn + c];
            m[j] = 0.f;
        }
        const float* w3row = &W3[(size_t)c * Dn];
        #pragma unroll 4
        for (int i = 0; i < Dn; ++i) {
            const float w3 = w3row[i];
            const float4 w1a = *(const float4*)&W1[(size_t)i*Hn + abase];
            m[0] = fmaf(w3, w1a.x, m[0]); m[1] = fmaf(w3, w1a.y, m[1]);
            m[2] = fmaf(w3, w1a.z, m[2]); m[3] = fmaf(w3, w1a.w, m[3]);
        }
        ushort4 pw, pc;
        unsigned short* PW = (unsigned short*)&pw;
        unsigned short* PC = (unsigned short*)&pc;
        #pragma unroll
        for (int j = 0; j < 4; ++j) {
            PW[j] = f2bf(w2v[j]);
            PC[j] = f2bf(w2v[j] * m[j]);
        }
        const size_t off = ((size_t)tix*64 + lane)*16 + jh*4;
        *(ushort4*)&WQ[off]     = pw;
        *(ushort4*)&WQ[off + 8] = pc;
    } else {
        const int tix = task - 1024;                   // 0..79 = (jt 0..4, ks 0..15)
        const int ks = tix & 15;
        const int j_out = (tix >> 4)*16 + n;
        const int abase = ks*32 + kg*8;
        short8 p;
        #pragma unroll
        for (int j = 0; j < 8; ++j)
            p[j] = (j_out < Dn) ? (short)f2bf(W3[(size_t)(abase + j)*Dn + j_out]) : (short)0;
        *(short8*)&W3P[((size_t)tix*64 + lane)*8] = p;
    }
}

// ============ k_fused: phases A+B+C, grid 256 x 1024 (verified structure) ============
// NEW this round: phase-B warmup WQ frags (ring slots 0,1) + phase-C's first
// W3P frag are loaded BEFORE phase A, so their remote-L2/L3 first-touch
// latency hides under phase A's FMA work instead of sitting serial after it.
__global__ __launch_bounds__(1024, 4) void k_fused(
    const float* __restrict__ xs, const float* __restrict__ tt,
    const float* __restrict__ W1, const float* __restrict__ b1,
    const unsigned short* __restrict__ WQ, const float* __restrict__ b2,
    const unsigned short* __restrict__ W3P, const float* __restrict__ b3,
    float* __restrict__ out)
{
    __shared__ float sX[67*16];                          // x~^T staging [i][r]
    __shared__ __align__(16) unsigned short sA[8192];    // h1 hi A-frags (16 KB)
    __shared__ __align__(16) unsigned short sS[8192];    // s1 A-frags   (16 KB)
    __shared__ __align__(16) unsigned short sH[8192];    // h2 hi (16 KB)
    __shared__ __align__(16) unsigned short sL[8192];    // h2 lo (16 KB)
    __shared__ float sRed[16*16];

    const int tid = threadIdx.x, lane = tid & 63, wv = tid >> 6;   // wv 0..15
    const int rt = blockIdx.x, r0 = rt*16;
    const int n = lane & 15, kg = lane >> 4;
    const int rot = (rt >> 3) & 15;
    const int ctb = wv*2;

    // ---- EARLY ISSUE: phase-B warmup WQ frags + phase-C first W3P frag ----
    short8 wA[3][2], wQ[3][2], aR[3], sR[3];
    #pragma unroll
    for (int p = 0; p < 2; ++p) {
        const int ksp = (p + rot) & 15;
        #pragma unroll
        for (int ti = 0; ti < 2; ++ti) {
            const size_t wo = ((size_t)((ctb + ti)*16 + ksp)*64 + lane)*16;
            wA[p][ti] = *(const short8*)&WQ[wo];
            wQ[p][ti] = *(const short8*)&WQ[wo + 8];
        }
    }
    short8 wf[2];
    if (wv < 5)
        wf[0] = *(const short8*)&W3P[((size_t)(wv*16 + rot)*64 + lane)*8];

    // ---- stage x~^T (row 66 = t) into sX[i*16 + r] ----
    for (int idx = tid; idx < 67*16; idx += 1024) {
        const int i = idx >> 4, r = idx & 15;
        sX[idx] = (i < Dn) ? xs[(size_t)(r0+r)*Dn + i] : tt[r0+r];
    }
    __syncthreads();

    // ---- phase A: z1 = [x,t]@W1 + b1 (fp32 VALU); wave wv owns ks-tile wv ----
    {
        const int rg = lane & 7, cg = lane >> 3;
        const int ks = wv;
        const int c0 = ks*32 + cg*4;
        const int irot = (rt >> 3) & 31;
        float z[2][4];
        {
            const float4 b4 = *(const float4*)&b1[c0];
            z[0][0]=b4.x; z[0][1]=b4.y; z[0][2]=b4.z; z[0][3]=b4.w;
            z[1][0]=b4.x; z[1][1]=b4.y; z[1][2]=b4.z; z[1][3]=b4.w;
        }
        #pragma unroll 4
        for (int s = 0; s < 67; ++s) {
            int i = s + irot; if (i >= 67) i -= 67;
            const float2 xf = *(const float2*)&sX[i*16 + 2*rg];
            const float4 wA1 = *(const float4*)&W1[(size_t)i*Hn + c0];
            const float ww[4] = {wA1.x, wA1.y, wA1.z, wA1.w};
            #pragma unroll
            for (int j = 0; j < 4; ++j) {
                z[0][j] = fmaf(xf.x, ww[j], z[0][j]);
                z[1][j] = fmaf(xf.y, ww[j], z[1][j]);
            }
        }
        const int kgrp = cg >> 1, joff = (cg & 1)*4;
        #pragma unroll
        for (int rr = 0; rr < 2; ++rr) {
            const int r = 2*rg + rr;
            ushort4 phi, ps;
            unsigned short* PH = (unsigned short*)&phi;
            unsigned short* PS = (unsigned short*)&ps;
            #pragma unroll
            for (int j = 0; j < 4; ++j) {
                const float zv = z[rr][j];
                const float sg = 1.f / (1.f + __expf(-zv));
                PH[j] = f2bf(zv * sg);
                PS[j] = f2bf(sg * (1.f + zv * (1.f - sg)));
            }
            const int off = (ks*64 + r + 16*kgrp)*8 + joff;
            *(ushort4*)&sA[off] = phi;
            *(ushort4*)&sS[off] = ps;
        }
    }
    __syncthreads();

    // ---- phase B: z2 = h1hi@W2 + b2, v = s1'@Cmat; depth-2 ring prefetch ----
    f32x4 zac[2], vac[2];
    #pragma unroll
    for (int ti = 0; ti < 2; ++ti) {
        const float bz = b2[(ctb + ti)*16 + n];
        zac[ti] = (f32x4){bz, bz, bz, bz};
        vac[ti] = (f32x4){0.f, 0.f, 0.f, 0.f};
    }
    #pragma unroll
    for (int p = 0; p < 2; ++p) {
        const int ksp = (p + rot) & 15;
        aR[p] = *(const short8*)&sA[(ksp*64 + lane)*8];
        sR[p] = *(const short8*)&sS[(ksp*64 + lane)*8];
    }
    #pragma unroll
    for (int s = 0; s < 16; ++s) {
        const int cur = s % 3;
        if (s < 14) {
            const int nx = (s + 2) % 3;
            const int ksn = (s + 2 + rot) & 15;
            aR[nx] = *(const short8*)&sA[(ksn*64 + lane)*8];
            sR[nx] = *(const short8*)&sS[(ksn*64 + lane)*8];
            #pragma unroll
            for (int ti = 0; ti < 2; ++ti) {
                const size_t wo = ((size_t)((ctb + ti)*16 + ksn)*64 + lane)*16;
                wA[nx][ti] = *(const short8*)&WQ[wo];
                wQ[nx][ti] = *(const short8*)&WQ[wo + 8];
            }
        }
        #pragma unroll
        for (int ti = 0; ti < 2; ++ti) {
            zac[ti] = __builtin_amdgcn_mfma_f32_16x16x32_bf16(aR[cur], wA[cur][ti], zac[ti], 0, 0, 0);
            vac[ti] = __builtin_amdgcn_mfma_f32_16x16x32_bf16(sR[cur], wQ[cur][ti], vac[ti], 0, 0, 0);
        }
    }

    // ---- epilogue: h2 hi/lo -> LDS; dp partial reduce ----
    float dp[4] = {0.f, 0.f, 0.f, 0.f};
    #pragma unroll
    for (int ti = 0; ti < 2; ++ti) {
        const int c = (ctb + ti)*16 + n;
        const int ks2 = c >> 5, kg2 = (c >> 3) & 3, j2 = c & 7;
        #pragma unroll
        for (int q = 0; q < 4; ++q) {
            const float z2 = zac[ti][q];
            const float sg = 1.f / (1.f + __expf(-z2));
            const float h2 = z2 * sg;
            dp[q] = fmaf(sg * (1.f + z2 * (1.f - sg)), vac[ti][q], dp[q]);
            const unsigned short hh = f2bf(h2);
            const int o = (ks2*64 + (kg*4 + q) + 16*kg2)*8 + j2;
            sH[o] = hh;
            sL[o] = f2bf(h2 - bf2f(hh));
        }
    }
    #pragma unroll
    for (int q = 0; q < 4; ++q) {
        float v = dp[q];
        v += __shfl_xor(v, 1, 64);
        v += __shfl_xor(v, 2, 64);
        v += __shfl_xor(v, 4, 64);
        v += __shfl_xor(v, 8, 64);
        if (n == 0) sRed[wv*16 + kg*4 + q] = v;
    }
    __syncthreads();

    // ---- divergence finalize ----
    if (tid < 16) {
        float s = 0.f;
        #pragma unroll
        for (int q = 0; q < 16; ++q) s += sRed[q*16 + tid];
        out[(size_t)Bn*Dn + r0 + tid] = -s;
    }

    // ---- phase C: out = h2 @ W3 + b3 (waves 0..4); depth-1 W3P prefetch ----
    if (wv < 5) {
        const int jt = wv;
        const int j = jt*16 + n;
        const float bj = (j < Dn) ? b3[j] : 0.f;
        f32x4 oac = (f32x4){bj, bj, bj, bj};
        #pragma unroll
        for (int s = 0; s < 16; ++s) {
            const int cur = s & 1;
            if (s < 15) {
                const int ksn = (s + 1 + rot) & 15;
                wf[cur ^ 1] = *(const short8*)&W3P[((size_t)(jt*16 + ksn)*64 + lane)*8];
            }
            const int ks = (s + rot) & 15;
            const int aoff = (ks*64 + lane)*8;
            const short8 ahi = *(const short8*)&sH[aoff];
            const short8 alo = *(const short8*)&sL[aoff];
            oac = __builtin_amdgcn_mfma_f32_16x16x32_bf16(ahi, wf[cur], oac, 0, 0, 0);
            oac = __builtin_amdgcn_mfma_f32_16x16x32_bf16(alo, wf[cur], oac, 0, 0, 0);
        }
        if (j < Dn) {
            #pragma unroll
            for (int q = 0; q < 4; ++q)
                out[(size_t)(r0 + kg*4 + q)*Dn + j] = oac[q];
        }
    }
}

extern "C" void kernel_launch(void* const* d_in, const int* in_sizes, int n_in,
                              void* d_out, int out_size, void* d_ws, size_t ws_size,
                              hipStream_t stream)
{
    const float* xs = (const float*)d_in[0];
    const float* t  = (const float*)d_in[1];
    const float* W1 = (const float*)d_in[2];
    const float* b1 = (const float*)d_in[3];
    const float* W2 = (const float*)d_in[4];
    const float* b2 = (const float*)d_in[5];
    const float* W3 = (const float*)d_in[6];
    const float* b3 = (const float*)d_in[7];
    float* out = (float*)d_out;

    char* ws = (char*)d_ws;
    unsigned short* WQ  = (unsigned short*)(ws);             // 1 MB interleaved W2|Cm
    unsigned short* W3P = (unsigned short*)(ws + 1048576);   // 80 KB

    k_pack <<<1104, 64,  0, stream>>>(W1, W2, W3, WQ, W3P);
    k_fused<<<256, 1024, 0, stream>>>(xs, t, W1, b1, WQ, b2, W3P, b3, out);
}

// Round 9
// 97.497 us; speedup vs baseline: 2.4601x; 1.0589x over previous
//
#include <hip/hip_runtime.h>

#define Bn 4096
#define Dn 66
#define Hn 512

typedef __attribute__((ext_vector_type(8))) short short8;
typedef __attribute__((ext_vector_type(4))) float f32x4;

__device__ __forceinline__ unsigned short f2bf(float x) {
    union { float f; unsigned u; } v; v.f = x;
    unsigned r = v.u + 0x7fffu + ((v.u >> 16) & 1u);   // RNE
    return (unsigned short)(r >> 16);
}
__device__ __forceinline__ float bf2f(unsigned short h) {
    union { float f; unsigned u; } v; v.u = ((unsigned)h) << 16; return v.f;
}

// Layouts (unchanged from verified kernels):
//   A-frag tile ks: lane l holds A[l&15][ks*32 + (l>>4)*8 + j]  at (ks*64 + l)*8 + j
//   WQ interleaved B-frag tile (ct, ks): W2-frag at ((ct*16+ks)*64+l)*16 + 0..7,
//       Cm-frag at +8..15
//   W3P B-frag tile (jt, ks): ((jt*16+ks)*64 + l)*8 + j

// ============ k_pack (1104 blocks x 64): one wave-task per block ============
// task = blockIdx.x:
//   0..1023  : WQ half-tile: tix = t>>1 (ct,ks), jh = t&1 -> j's jh*4..jh*4+3
//   1024..1103: W3P tile tix = t-1024
// bounds (64,4): 128-VGPR cap (round-8's (64,8) capped at 64 VGPR -> constrained
// the unrolled loop). unroll 11 (66 = 6x11): ~22 loads hoistable per group.
__global__ __launch_bounds__(64, 4) void k_pack(
    const float* __restrict__ W1, const float* __restrict__ W2,
    const float* __restrict__ W3,
    unsigned short* __restrict__ WQ, unsigned short* __restrict__ W3P)
{
    const int lane = threadIdx.x & 63;
    const int task = blockIdx.x;                       // 0..1103
    const int n = lane & 15, kg = lane >> 4;

    if (task < 1024) {
        const int tix = task >> 1;                     // 0..511 = (ct, ks)
        const int jh  = task & 1;
        const int ct = tix >> 4, ks = tix & 15;
        const int c = ct*16 + n;
        const int abase = ks*32 + kg*8 + jh*4;
        float w2v[4], m[4];
        #pragma unroll
        for (int j = 0; j < 4; ++j) {
            w2v[j] = W2[(size_t)(abase + j)*Hn + c];
            m[j] = 0.f;
        }
        const float* w3row = &W3[(size_t)c * Dn];
        #pragma unroll 11
        for (int i = 0; i < Dn; ++i) {
            const float w3 = w3row[i];
            const float4 w1a = *(const float4*)&W1[(size_t)i*Hn + abase];
            m[0] = fmaf(w3, w1a.x, m[0]); m[1] = fmaf(w3, w1a.y, m[1]);
            m[2] = fmaf(w3, w1a.z, m[2]); m[3] = fmaf(w3, w1a.w, m[3]);
        }
        ushort4 pw, pc;
        unsigned short* PW = (unsigned short*)&pw;
        unsigned short* PC = (unsigned short*)&pc;
        #pragma unroll
        for (int j = 0; j < 4; ++j) {
            PW[j] = f2bf(w2v[j]);
            PC[j] = f2bf(w2v[j] * m[j]);
        }
        const size_t off = ((size_t)tix*64 + lane)*16 + jh*4;
        *(ushort4*)&WQ[off]     = pw;
        *(ushort4*)&WQ[off + 8] = pc;
    } else {
        const int tix = task - 1024;                   // 0..79 = (jt 0..4, ks 0..15)
        const int ks = tix & 15;
        const int j_out = (tix >> 4)*16 + n;
        const int abase = ks*32 + kg*8;
        short8 p;
        #pragma unroll
        for (int j = 0; j < 8; ++j)
            p[j] = (j_out < Dn) ? (short)f2bf(W3[(size_t)(abase + j)*Dn + j_out]) : (short)0;
        *(short8*)&W3P[((size_t)tix*64 + lane)*8] = p;
    }
}

// ============ k_fused: phases A+B+C, grid 256 x 1024 (verified structure) ============
// This round: phase-B WQ ring deepened to 3-ahead (ring[4], static indices under
// full unroll); all 3 warmup WQ slots + phase-C first W3P frag issued BEFORE
// phase A so first-touch latency hides under phase A's FMA work. A/S LDS reads
// stay 1-ahead (ring[2], LDS latency is short; saves 16 VGPR vs full ring).
__global__ __launch_bounds__(1024, 4) void k_fused(
    const float* __restrict__ xs, const float* __restrict__ tt,
    const float* __restrict__ W1, const float* __restrict__ b1,
    const unsigned short* __restrict__ WQ, const float* __restrict__ b2,
    const unsigned short* __restrict__ W3P, const float* __restrict__ b3,
    float* __restrict__ out)
{
    __shared__ float sX[67*16];                          // x~^T staging [i][r]
    __shared__ __align__(16) unsigned short sA[8192];    // h1 hi A-frags (16 KB)
    __shared__ __align__(16) unsigned short sS[8192];    // s1 A-frags   (16 KB)
    __shared__ __align__(16) unsigned short sH[8192];    // h2 hi (16 KB)
    __shared__ __align__(16) unsigned short sL[8192];    // h2 lo (16 KB)
    __shared__ float sRed[16*16];

    const int tid = threadIdx.x, lane = tid & 63, wv = tid >> 6;   // wv 0..15
    const int rt = blockIdx.x, r0 = rt*16;
    const int n = lane & 15, kg = lane >> 4;
    const int rot = (rt >> 3) & 15;
    const int ctb = wv*2;

    // ---- EARLY ISSUE: 3 warmup WQ slots + phase-C first W3P frag ----
    short8 wA[4][2], wQ[4][2], aR[2], sR[2];
    #pragma unroll
    for (int p = 0; p < 3; ++p) {
        const int ksp = (p + rot) & 15;
        #pragma unroll
        for (int ti = 0; ti < 2; ++ti) {
            const size_t wo = ((size_t)((ctb + ti)*16 + ksp)*64 + lane)*16;
            wA[p][ti] = *(const short8*)&WQ[wo];
            wQ[p][ti] = *(const short8*)&WQ[wo + 8];
        }
    }
    short8 wf[2];
    if (wv < 5)
        wf[0] = *(const short8*)&W3P[((size_t)(wv*16 + rot)*64 + lane)*8];

    // ---- stage x~^T (row 66 = t) into sX[i*16 + r] ----
    for (int idx = tid; idx < 67*16; idx += 1024) {
        const int i = idx >> 4, r = idx & 15;
        sX[idx] = (i < Dn) ? xs[(size_t)(r0+r)*Dn + i] : tt[r0+r];
    }
    __syncthreads();

    // ---- phase A: z1 = [x,t]@W1 + b1 (fp32 VALU); wave wv owns ks-tile wv ----
    {
        const int rg = lane & 7, cg = lane >> 3;
        const int ks = wv;
        const int c0 = ks*32 + cg*4;
        const int irot = (rt >> 3) & 31;
        float z[2][4];
        {
            const float4 b4 = *(const float4*)&b1[c0];
            z[0][0]=b4.x; z[0][1]=b4.y; z[0][2]=b4.z; z[0][3]=b4.w;
            z[1][0]=b4.x; z[1][1]=b4.y; z[1][2]=b4.z; z[1][3]=b4.w;
        }
        #pragma unroll 4
        for (int s = 0; s < 67; ++s) {
            int i = s + irot; if (i >= 67) i -= 67;
            const float2 xf = *(const float2*)&sX[i*16 + 2*rg];
            const float4 wA1 = *(const float4*)&W1[(size_t)i*Hn + c0];
            const float ww[4] = {wA1.x, wA1.y, wA1.z, wA1.w};
            #pragma unroll
            for (int j = 0; j < 4; ++j) {
                z[0][j] = fmaf(xf.x, ww[j], z[0][j]);
                z[1][j] = fmaf(xf.y, ww[j], z[1][j]);
            }
        }
        const int kgrp = cg >> 1, joff = (cg & 1)*4;
        #pragma unroll
        for (int rr = 0; rr < 2; ++rr) {
            const int r = 2*rg + rr;
            ushort4 phi, ps;
            unsigned short* PH = (unsigned short*)&phi;
            unsigned short* PS = (unsigned short*)&ps;
            #pragma unroll
            for (int j = 0; j < 4; ++j) {
                const float zv = z[rr][j];
                const float sg = 1.f / (1.f + __expf(-zv));
                PH[j] = f2bf(zv * sg);
                PS[j] = f2bf(sg * (1.f + zv * (1.f - sg)));
            }
            const int off = (ks*64 + r + 16*kgrp)*8 + joff;
            *(ushort4*)&sA[off] = phi;
            *(ushort4*)&sS[off] = ps;
        }
    }
    __syncthreads();

    // ---- phase B: z2 = h1hi@W2 + b2, v = s1'@Cmat; WQ 3-deep, A/S 1-deep ----
    f32x4 zac[2], vac[2];
    #pragma unroll
    for (int ti = 0; ti < 2; ++ti) {
        const float bz = b2[(ctb + ti)*16 + n];
        zac[ti] = (f32x4){bz, bz, bz, bz};
        vac[ti] = (f32x4){0.f, 0.f, 0.f, 0.f};
    }
    {
        const int ks0 = rot;
        aR[0] = *(const short8*)&sA[(ks0*64 + lane)*8];
        sR[0] = *(const short8*)&sS[(ks0*64 + lane)*8];
    }
    #pragma unroll
    for (int s = 0; s < 16; ++s) {
        const int cur = s & 3;          // static under full unroll
        const int la  = s & 1;
        if (s < 13) {
            const int nx = (s + 3) & 3;
            const int ksn = (s + 3 + rot) & 15;
            #pragma unroll
            for (int ti = 0; ti < 2; ++ti) {
                const size_t wo = ((size_t)((ctb + ti)*16 + ksn)*64 + lane)*16;
                wA[nx][ti] = *(const short8*)&WQ[wo];
                wQ[nx][ti] = *(const short8*)&WQ[wo + 8];
            }
        }
        if (s < 15) {
            const int ksn = (s + 1 + rot) & 15;
            aR[la ^ 1] = *(const short8*)&sA[(ksn*64 + lane)*8];
            sR[la ^ 1] = *(const short8*)&sS[(ksn*64 + lane)*8];
        }
        #pragma unroll
        for (int ti = 0; ti < 2; ++ti) {
            zac[ti] = __builtin_amdgcn_mfma_f32_16x16x32_bf16(aR[la], wA[cur][ti], zac[ti], 0, 0, 0);
            vac[ti] = __builtin_amdgcn_mfma_f32_16x16x32_bf16(sR[la], wQ[cur][ti], vac[ti], 0, 0, 0);
        }
    }

    // ---- epilogue: h2 hi/lo -> LDS; dp partial reduce ----
    float dp[4] = {0.f, 0.f, 0.f, 0.f};
    #pragma unroll
    for (int ti = 0; ti < 2; ++ti) {
        const int c = (ctb + ti)*16 + n;
        const int ks2 = c >> 5, kg2 = (c >> 3) & 3, j2 = c & 7;
        #pragma unroll
        for (int q = 0; q < 4; ++q) {
            const float z2 = zac[ti][q];
            const float sg = 1.f / (1.f + __expf(-z2));
            const float h2 = z2 * sg;
            dp[q] = fmaf(sg * (1.f + z2 * (1.f - sg)), vac[ti][q], dp[q]);
            const unsigned short hh = f2bf(h2);
            const int o = (ks2*64 + (kg*4 + q) + 16*kg2)*8 + j2;
            sH[o] = hh;
            sL[o] = f2bf(h2 - bf2f(hh));
        }
    }
    #pragma unroll
    for (int q = 0; q < 4; ++q) {
        float v = dp[q];
        v += __shfl_xor(v, 1, 64);
        v += __shfl_xor(v, 2, 64);
        v += __shfl_xor(v, 4, 64);
        v += __shfl_xor(v, 8, 64);
        if (n == 0) sRed[wv*16 + kg*4 + q] = v;
    }
    __syncthreads();

    // ---- divergence finalize ----
    if (tid < 16) {
        float s = 0.f;
        #pragma unroll
        for (int q = 0; q < 16; ++q) s += sRed[q*16 + tid];
        out[(size_t)Bn*Dn + r0 + tid] = -s;
    }

    // ---- phase C: out = h2 @ W3 + b3 (waves 0..4); depth-1 W3P prefetch ----
    if (wv < 5) {
        const int jt = wv;
        const int j = jt*16 + n;
        const float bj = (j < Dn) ? b3[j] : 0.f;
        f32x4 oac = (f32x4){bj, bj, bj, bj};
        #pragma unroll
        for (int s = 0; s < 16; ++s) {
            const int cur = s & 1;
            if (s < 15) {
                const int ksn = (s + 1 + rot) & 15;
                wf[cur ^ 1] = *(const short8*)&W3P[((size_t)(jt*16 + ksn)*64 + lane)*8];
            }
            const int ks = (s + rot) & 15;
            const int aoff = (ks*64 + lane)*8;
            const short8 ahi = *(const short8*)&sH[aoff];
            const short8 alo = *(const short8*)&sL[aoff];
            oac = __builtin_amdgcn_mfma_f32_16x16x32_bf16(ahi, wf[cur], oac, 0, 0, 0);
            oac = __builtin_amdgcn_mfma_f32_16x16x32_bf16(alo, wf[cur], oac, 0, 0, 0);
        }
        if (j < Dn) {
            #pragma unroll
            for (int q = 0; q < 4; ++q)
                out[(size_t)(r0 + kg*4 + q)*Dn + j] = oac[q];
        }
    }
}

extern "C" void kernel_launch(void* const* d_in, const int* in_sizes, int n_in,
                              void* d_out, int out_size, void* d_ws, size_t ws_size,
                              hipStream_t stream)
{
    const float* xs = (const float*)d_in[0];
    const float* t  = (const float*)d_in[1];
    const float* W1 = (const float*)d_in[2];
    const float* b1 = (const float*)d_in[3];
    const float* W2 = (const float*)d_in[4];
    const float* b2 = (const float*)d_in[5];
    const float* W3 = (const float*)d_in[6];
    const float* b3 = (const float*)d_in[7];
    float* out = (float*)d_out;

    char* ws = (char*)d_ws;
    unsigned short* WQ  = (unsigned short*)(ws);             // 1 MB interleaved W2|Cm
    unsigned short* W3P = (unsigned short*)(ws + 1048576);   // 80 KB

    k_pack <<<1104, 64,  0, stream>>>(W1, W2, W3, WQ, W3P);
    k_fused<<<256, 1024, 0, stream>>>(xs, t, W1, b1, WQ, b2, W3P, b3, out);
}